// Round 8
// baseline (786.619 us; speedup 1.0000x reference)
//
#include <hip/hip_runtime.h>
#include <hip/hip_bf16.h>
#include <hip/hip_cooperative_groups.h>

namespace cg = cooperative_groups;

typedef unsigned short u16;
typedef u16 u16x4 __attribute__((ext_vector_type(4)));
typedef u16 u16x8 __attribute__((ext_vector_type(8)));
typedef __bf16 bf16x8 __attribute__((ext_vector_type(8)));
typedef float f32x4 __attribute__((ext_vector_type(4)));

__device__ __forceinline__ u16 f2bf(float f) {
  unsigned u = __float_as_uint(f);
  u += 0x7FFFu + ((u >> 16) & 1u);   // round-to-nearest-even
  return (u16)(u >> 16);
}
__device__ __forceinline__ float bf2f(u16 h) {
  return __uint_as_float(((unsigned)h) << 16);
}
__device__ __forceinline__ float tanh_fast(float x) {
  float t = __expf(2.0f * x);
  return 1.0f - 2.0f / (t + 1.0f);
}
__device__ __forceinline__ float sigmoid_fast(float x) {
  return 1.0f / (1.0f + __expf(-x));
}

// async global->LDS, 16B per lane. Dest is wave-uniform base + lane*16; our
// per-lane dest (= base + tid*8 u16) is linear in tid, matching exactly.
__device__ __forceinline__ void glds16(const u16* g, u16* l) {
  __builtin_amdgcn_global_load_lds(
      (const __attribute__((address_space(1))) unsigned int*)g,
      (__attribute__((address_space(3))) unsigned int*)l, 16, 0, 0);
}

__device__ __forceinline__ void cvt4(const float* __restrict__ s, u16* __restrict__ d, int q) {
  float4 v = ((const float4*)s)[q];
  u16x4 o = { f2bf(v.x), f2bf(v.y), f2bf(v.z), f2bf(v.w) };
  ((u16x4*)d)[q] = o;
}

struct FP {
  const float *obs, *We, *be, *aW, *ab, *W1, *b1, *W2, *b2, *W3, *b3;
  float* out;
  u16 *We_b, *Wd_b, *W1_b, *W2_b, *obs_b, *e_b, *sa_b, *h1_b;
  float* bd;
};

// ---------------- prep body: fp32->bf16 casts + attn weight-diff + zero v ----------------
// grid-stride over 2,883,584 float4-quads with 131072 threads (22 iters).
__device__ void prep_body(const FP& p, int t0) {
  for (int q0 = t0; q0 < 2883584; q0 += 131072) {
    int q = q0;
    if (q < 1024) ((float4*)p.out)[q] = (float4){0.f, 0.f, 0.f, 0.f};  // zero v[4096]
    if (q < 1048576) { cvt4(p.obs, p.obs_b, q); continue; }            // 4096*1024
    q -= 1048576;
    if (q < 131072) { cvt4(p.We, p.We_b, q); continue; }               // 512*1024
    q -= 131072;
    if (q < 524288) { cvt4(p.W1, p.W1_b, q); continue; }               // 2048*1024
    q -= 524288;
    if (q < 1048576) { cvt4(p.W2, p.W2_b, q); continue; }              // 2048*2048
    q -= 1048576;
    {                                                                   // Wd: 1024*512
      int i0 = q * 4;
      int o = i0 >> 9, e0 = i0 & 511;
      const float* s = p.aW + (size_t)o * 1024 + e0 * 2;
      float4 v0 = *(const float4*)s;
      float4 v1 = *(const float4*)(s + 4);
      u16x4 od = { f2bf(v0.y - v0.x), f2bf(v0.w - v0.z),
                   f2bf(v1.y - v1.x), f2bf(v1.w - v1.z) };
      *(u16x4*)(p.Wd_b + i0) = od;
      if (q < 256) {                                                    // bd: 1024
        float4 a0 = *(const float4*)(p.ab + q * 8);
        float4 a1 = *(const float4*)(p.ab + q * 8 + 4);
        float4 ob = { a0.y - a0.x, a0.w - a0.z, a1.y - a1.x, a1.w - a1.z };
        *(float4*)(p.bd + q * 4) = ob;
      }
    }
  }
}

// ---------------- R2-proven GEMM phase as a device function ----------------
// C = A[M,K] * Bt[N,K]^T, BK=64. 2-phase dbuf, glds staging, both-sides XOR
// swizzle (measured 0 bank conflicts), one vmcnt-drain barrier per K-step.
// EP 0: outb = bf16(tanh(x + bias[col]))
// EP 1: att = sigmoid(x + bias[col]); outf = att; sa = bf16(obs_b * att)
// EP 2: fused v-dot: atomicAdd(vout[row], sum_col tanh(x+bias)*W3[col])
template <int BM, int BN, int EP>
__device__ void gemm_phase(const u16* __restrict__ A, const u16* __restrict__ Bt,
                           int N, int K,
                           const float* __restrict__ bias,
                           u16* __restrict__ outb, float* __restrict__ outf,
                           const u16* __restrict__ obsb, u16* __restrict__ sa,
                           const float* __restrict__ W3, const float* __restrict__ b3,
                           float* __restrict__ vout,
                           u16* __restrict__ As0, u16* __restrict__ Bs0,
                           u16* __restrict__ As1, u16* __restrict__ Bs1,
                           int bm, int bn) {
  constexpr int CA = BM / 32;
  constexpr int CB = BN / 32;
  constexpr int MI = BM / 32;
  constexpr int NJ = BN / 32;

  const int tid = threadIdx.x;
  const int lane = tid & 63;
  const int wave = tid >> 6;

  const int r0 = tid >> 3;
  const int kcs = ((tid & 7) ^ (r0 & 7)) * 8;    // pre-swizzled source chunk

  const u16* gA = A + (size_t)(bm * BM + r0) * K + kcs;
  const u16* gB = Bt + (size_t)(bn * BN + r0) * K + kcs;

  const int wm = (wave >> 1) * (BM / 2);
  const int wn = (wave & 1) * (BN / 2);
  const int fr = lane & 15;
  const int hi = lane >> 4;
  const int frx = fr & 7;

  f32x4 acc[MI][NJ];
#pragma unroll
  for (int i = 0; i < MI; ++i)
#pragma unroll
    for (int j = 0; j < NJ; ++j)
      acc[i][j] = (f32x4){0.f, 0.f, 0.f, 0.f};

  auto stage = [&](u16* __restrict__ dA, u16* __restrict__ dB) {
#pragma unroll
    for (int q = 0; q < CA; ++q)
      glds16(gA + (size_t)q * 32 * K, dA + tid * 8 + q * 2048);
#pragma unroll
    for (int q = 0; q < CB; ++q)
      glds16(gB + (size_t)q * 32 * K, dB + tid * 8 + q * 2048);
    gA += 64; gB += 64;
  };

  auto compute = [&](const u16* sA, const u16* sB) {
#pragma unroll
    for (int s = 0; s < 2; ++s) {
      const int ck = ((s * 4 + hi) ^ frx) * 8;
      bf16x8 a[MI], b[NJ];
#pragma unroll
      for (int i = 0; i < MI; ++i)
        a[i] = *(const bf16x8*)(sA + (wm + i * 16 + fr) * 64 + ck);
#pragma unroll
      for (int j = 0; j < NJ; ++j)
        b[j] = *(const bf16x8*)(sB + (wn + j * 16 + fr) * 64 + ck);
#pragma unroll
      for (int i = 0; i < MI; ++i)
#pragma unroll
        for (int j = 0; j < NJ; ++j)
          acc[i][j] = __builtin_amdgcn_mfma_f32_16x16x32_bf16(a[i], b[j], acc[i][j], 0, 0, 0);
    }
  };

  const int T = K >> 6;                // call sites: T even
  stage(As0, Bs0);
  __syncthreads();
  for (int k = 0; k < T; k += 2) {
    stage(As1, Bs1);
    compute(As0, Bs0);
    __syncthreads();
    if (k + 2 < T) stage(As0, Bs0);
    compute(As1, Bs1);
    __syncthreads();
  }

  if constexpr (EP == 2) {
    float vpart[MI][4];
#pragma unroll
    for (int i = 0; i < MI; ++i)
#pragma unroll
      for (int r = 0; r < 4; ++r) vpart[i][r] = 0.f;
#pragma unroll
    for (int j = 0; j < NJ; ++j) {
      const int col = bn * BN + wn + j * 16 + fr;
      const float bv = bias[col];
      const float w3 = W3[col];
#pragma unroll
      for (int i = 0; i < MI; ++i)
#pragma unroll
        for (int r = 0; r < 4; ++r)
          vpart[i][r] += tanh_fast(acc[i][j][r] + bv) * w3;
    }
    const bool lead = (fr == 0);
    const bool addb = (bn == 0) && ((wave & 1) == 0);
#pragma unroll
    for (int i = 0; i < MI; ++i)
#pragma unroll
      for (int r = 0; r < 4; ++r) {
        float p = vpart[i][r];
        p += __shfl_xor(p, 8);
        p += __shfl_xor(p, 4);
        p += __shfl_xor(p, 2);
        p += __shfl_xor(p, 1);
        if (lead) {
          const int row = bm * BM + wm + i * 16 + hi * 4 + r;
          atomicAdd(vout + row, addb ? p + b3[0] : p);
        }
      }
  } else {
#pragma unroll
    for (int j = 0; j < NJ; ++j) {
      const int col = bn * BN + wn + j * 16 + fr;
      const float bv = bias[col];
#pragma unroll
      for (int i = 0; i < MI; ++i) {
#pragma unroll
        for (int r = 0; r < 4; ++r) {
          const int row = bm * BM + wm + i * 16 + hi * 4 + r;
          const float x = acc[i][j][r] + bv;
          const size_t idx = (size_t)row * N + col;
          if constexpr (EP == 0) {
            outb[idx] = f2bf(tanh_fast(x));
          } else {
            const float att = sigmoid_fast(x);
            outf[idx] = att;
            sa[idx] = f2bf(bf2f(obsb[idx]) * att);
          }
        }
      }
    }
  }
}

// ---------------- fused cooperative kernel (path A) ----------------
// R8: retry of R7 with (1) release+acquire fences around every grid.sync
// (reader-side __threadfence invalidates stale per-XCD L2/L1 lines cached in
// previous launch iterations) and (2) host-side error check + fallback.
__global__ __launch_bounds__(256, 2)
void fused(FP p) {
  __shared__ __align__(16) u16 L[4][8192];     // 64 KB, reused by all phases
  const int bid = blockIdx.x;
  const int tid = threadIdx.x;
  cg::grid_group grid = cg::this_grid();

  prep_body(p, bid * 256 + tid);
  __threadfence();
  grid.sync();
  __threadfence();

  // G1: e = tanh(obs @ We^T + be)  [4096,512], 64x64, grid 64x8
  gemm_phase<64, 64, 0>(p.obs_b, p.We_b, 512, 1024, p.be,
                        p.e_b, nullptr, nullptr, nullptr, nullptr, nullptr, nullptr,
                        L[0], L[1], L[2], L[3], bid & 63, bid >> 6);
  __threadfence();
  grid.sync();
  __threadfence();

  // G2: att = sigmoid(e @ Wd^T + bd); sa = obs*att  [4096,1024], 128x64
  gemm_phase<128, 64, 1>(p.e_b, p.Wd_b, 1024, 512, p.bd,
                         nullptr, p.out + 4096, p.obs_b, p.sa_b, nullptr, nullptr, nullptr,
                         L[0], L[1], L[2], L[3], bid & 31, bid >> 5);
  __threadfence();
  grid.sync();
  __threadfence();

  // G3: h1 = tanh(sa @ W1^T + b1)  [4096,2048], 128x128
  gemm_phase<128, 128, 0>(p.sa_b, p.W1_b, 2048, 1024, p.b1,
                          p.h1_b, nullptr, nullptr, nullptr, nullptr, nullptr, nullptr,
                          L[0], L[1], L[2], L[3], bid & 31, bid >> 5);
  __threadfence();
  grid.sync();
  __threadfence();

  // G4+v: v = tanh(h1 @ W2^T + b2) @ W3 + b3 (h2 never stored)
  gemm_phase<128, 128, 2>(p.h1_b, p.W2_b, 2048, 2048, p.b2,
                          nullptr, nullptr, nullptr, nullptr, p.W3, p.b3, p.out,
                          L[0], L[1], L[2], L[3], bid & 31, bid >> 5);
}

// ---------------- fallback kernels (path B = exact R2 sequence) ----------------
__global__ __launch_bounds__(256)
void prep_k(FP p) {
  prep_body(p, blockIdx.x * 256 + threadIdx.x);
}

template <int BM, int BN, int EP>
__global__ __launch_bounds__(256, 2)
void gemm_g(const u16* __restrict__ A, const u16* __restrict__ Bt,
            int N, int K, const float* __restrict__ bias,
            u16* __restrict__ outb, float* __restrict__ outf,
            const u16* __restrict__ obsb, u16* __restrict__ sa,
            const float* __restrict__ W3, const float* __restrict__ b3,
            float* __restrict__ vout) {
  __shared__ __align__(16) u16 L[4][8192];
  gemm_phase<BM, BN, EP>(A, Bt, N, K, bias, outb, outf, obsb, sa, W3, b3, vout,
                         L[0], L[1], L[2], L[3], blockIdx.x, blockIdx.y);
}

extern "C" void kernel_launch(void* const* d_in, const int* in_sizes, int n_in,
                              void* d_out, int out_size, void* d_ws, size_t ws_size,
                              hipStream_t stream) {
  char* ws = (char*)d_ws;
  FP p;
  p.obs   = (const float*)d_in[0];   // [4096,1024]
  p.We    = (const float*)d_in[1];   // [512,1024]
  p.be    = (const float*)d_in[2];   // [512]
  p.aW    = (const float*)d_in[3];   // [1024,512,2]
  p.ab    = (const float*)d_in[4];   // [1024,2]
  p.W1    = (const float*)d_in[5];   // [2048,1024]
  p.b1    = (const float*)d_in[6];   // [2048]
  p.W2    = (const float*)d_in[7];   // [2048,2048]
  p.b2    = (const float*)d_in[8];   // [2048]
  p.W3    = (const float*)d_in[9];   // [1,2048]
  p.b3    = (const float*)d_in[10];  // [1]
  p.out   = (float*)d_out;           // [4096] v, then [4096,1024] attention

  p.We_b  = (u16*)(ws + 0x00000000);   // 1 MB
  p.Wd_b  = (u16*)(ws + 0x00100000);   // 1 MB
  p.W1_b  = (u16*)(ws + 0x00200000);   // 4 MB
  p.W2_b  = (u16*)(ws + 0x00600000);   // 8 MB
  p.bd    = (float*)(ws + 0x00E00000); // 4 KB
  p.obs_b = (u16*)(ws + 0x00E01000);   // 8 MB
  p.e_b   = (u16*)(ws + 0x01601000);   // 4 MB
  p.sa_b  = (u16*)(ws + 0x01A01000);   // 8 MB
  p.h1_b  = (u16*)(ws + 0x02201000);   // 16 MB (end ~50 MB; h2 never stored)

  void* args[] = { &p };
  hipError_t err = hipLaunchCooperativeKernel((const void*)fused, dim3(512), dim3(256),
                                              args, 0, stream);
  if (err != hipSuccess) {
    // Path B: exact R2 five-kernel sequence (189.9 us verified).
    prep_k<<<512, 256, 0, stream>>>(p);
    gemm_g<64, 64, 0><<<dim3(64, 8), 256, 0, stream>>>(
        p.obs_b, p.We_b, 512, 1024, p.be, p.e_b, nullptr, nullptr, nullptr,
        nullptr, nullptr, nullptr);
    gemm_g<128, 64, 1><<<dim3(32, 16), 256, 0, stream>>>(
        p.e_b, p.Wd_b, 1024, 512, p.bd, nullptr, p.out + 4096, p.obs_b, p.sa_b,
        nullptr, nullptr, nullptr);
    gemm_g<128, 128, 0><<<dim3(32, 16), 256, 0, stream>>>(
        p.sa_b, p.W1_b, 2048, 1024, p.b1, p.h1_b, nullptr, nullptr, nullptr,
        nullptr, nullptr, nullptr);
    gemm_g<128, 128, 2><<<dim3(32, 16), 256, 0, stream>>>(
        p.h1_b, p.W2_b, 2048, 2048, p.b2, nullptr, nullptr, nullptr, nullptr,
        p.W3, p.b3, p.out);
  }
}

// Round 9
// 196.507 us; speedup vs baseline: 4.0030x; 4.0030x over previous
//
#include <hip/hip_runtime.h>
#include <hip/hip_bf16.h>

typedef unsigned short u16;
typedef u16 u16x4 __attribute__((ext_vector_type(4)));
typedef u16 u16x8 __attribute__((ext_vector_type(8)));
typedef __bf16 bf16x8 __attribute__((ext_vector_type(8)));
typedef float f32x4 __attribute__((ext_vector_type(4)));

__device__ __forceinline__ u16 f2bf(float f) {
  unsigned u = __float_as_uint(f);
  u += 0x7FFFu + ((u >> 16) & 1u);   // round-to-nearest-even
  return (u16)(u >> 16);
}
__device__ __forceinline__ float bf2f(u16 h) {
  return __uint_as_float(((unsigned)h) << 16);
}
__device__ __forceinline__ float tanh_fast(float x) {
  float t = __expf(2.0f * x);
  return 1.0f - 2.0f / (t + 1.0f);
}
__device__ __forceinline__ float sigmoid_fast(float x) {
  return 1.0f / (1.0f + __expf(-x));
}

// async global->LDS, 16B per lane. Dest is wave-uniform base + lane*16; our
// per-lane dest (= base + tid*8 u16) is linear in tid, matching exactly.
__device__ __forceinline__ void glds16(const u16* g, u16* l) {
  __builtin_amdgcn_global_load_lds(
      (const __attribute__((address_space(1))) unsigned int*)g,
      (__attribute__((address_space(3))) unsigned int*)l, 16, 0, 0);
}

// ---------------- fused prep: fp32->bf16 casts + attn weight-diff + zero v ----------------
__device__ __forceinline__ void cvt4(const float* __restrict__ s, u16* __restrict__ d, int q) {
  float4 v = ((const float4*)s)[q];
  u16x4 o = { f2bf(v.x), f2bf(v.y), f2bf(v.z), f2bf(v.w) };
  ((u16x4*)d)[q] = o;
}

__global__ __launch_bounds__(256)
void prep_kernel(const float* __restrict__ obs, const float* __restrict__ We,
                 const float* __restrict__ W1, const float* __restrict__ W2,
                 const float* __restrict__ aW, const float* __restrict__ ab,
                 u16* __restrict__ obs_b, u16* __restrict__ We_b,
                 u16* __restrict__ W1_b, u16* __restrict__ W2_b,
                 u16* __restrict__ Wd, float* __restrict__ bd,
                 float* __restrict__ vzero) {
  int q = blockIdx.x * 256 + threadIdx.x;          // quad (4-element) index
  if (q < 1024) ((float4*)vzero)[q] = (float4){0.f, 0.f, 0.f, 0.f};  // zero v[4096]
  if (q < 1048576) { cvt4(obs, obs_b, q); return; }                 // 4096*1024
  q -= 1048576;
  if (q < 131072) { cvt4(We, We_b, q); return; }                    // 512*1024
  q -= 131072;
  if (q < 524288) { cvt4(W1, W1_b, q); return; }                    // 2048*1024
  q -= 524288;
  if (q < 1048576) { cvt4(W2, W2_b, q); return; }                   // 2048*2048
  q -= 1048576;
  if (q < 131072) {                                                  // Wd: 1024*512
    int i0 = q * 4;
    int o = i0 >> 9, e0 = i0 & 511;
    const float* p = aW + (size_t)o * 1024 + e0 * 2;
    float4 v0 = *(const float4*)p;
    float4 v1 = *(const float4*)(p + 4);
    u16x4 od = { f2bf(v0.y - v0.x), f2bf(v0.w - v0.z),
                 f2bf(v1.y - v1.x), f2bf(v1.w - v1.z) };
    *(u16x4*)(Wd + i0) = od;
    if (q < 256) {                                                   // bd: 1024
      float4 a0 = *(const float4*)(ab + q * 8);
      float4 a1 = *(const float4*)(ab + q * 8 + 4);
      float4 ob = { a0.y - a0.x, a0.w - a0.z, a1.y - a1.x, a1.w - a1.z };
      *(float4*)(bd + q * 4) = ob;
    }
  }
}

// ---------------- R2-proven 2-phase dbuf GEMM (G1/G2/G3) ----------------
// EP 0: outb = bf16(tanh(x + bias[col]))
// EP 1: att = sigmoid(x + bias[col]); outf = att; sa = bf16(obs_b * att)
template <int BM, int BN, int EP>
__global__ __launch_bounds__(256, 2)
void gemm_bt(const u16* __restrict__ A, const u16* __restrict__ Bt,
             int N, int K,
             const float* __restrict__ bias,
             u16* __restrict__ outb, float* __restrict__ outf,
             const u16* __restrict__ obsb, u16* __restrict__ sa) {
  constexpr int CA = BM / 32;
  constexpr int CB = BN / 32;
  constexpr int MI = BM / 32;
  constexpr int NJ = BN / 32;

  __shared__ __align__(16) u16 As0[BM * 64];
  __shared__ __align__(16) u16 Bs0[BN * 64];
  __shared__ __align__(16) u16 As1[BM * 64];
  __shared__ __align__(16) u16 Bs1[BN * 64];

  const int tid = threadIdx.x;
  const int lane = tid & 63;
  const int wave = tid >> 6;
  const int bm = blockIdx.x, bn = blockIdx.y;

  const int r0 = tid >> 3;
  const int kcs = ((tid & 7) ^ (r0 & 7)) * 8;    // pre-swizzled source chunk

  const u16* gA = A + (size_t)(bm * BM + r0) * K + kcs;
  const u16* gB = Bt + (size_t)(bn * BN + r0) * K + kcs;

  const int wm = (wave >> 1) * (BM / 2);
  const int wn = (wave & 1) * (BN / 2);
  const int fr = lane & 15;
  const int hi = lane >> 4;
  const int frx = fr & 7;

  f32x4 acc[MI][NJ];
#pragma unroll
  for (int i = 0; i < MI; ++i)
#pragma unroll
    for (int j = 0; j < NJ; ++j)
      acc[i][j] = (f32x4){0.f, 0.f, 0.f, 0.f};

  auto stage = [&](u16* __restrict__ dA, u16* __restrict__ dB) {
#pragma unroll
    for (int q = 0; q < CA; ++q)
      glds16(gA + (size_t)q * 32 * K, dA + tid * 8 + q * 2048);
#pragma unroll
    for (int q = 0; q < CB; ++q)
      glds16(gB + (size_t)q * 32 * K, dB + tid * 8 + q * 2048);
    gA += 64; gB += 64;
  };

  auto compute = [&](const u16* sA, const u16* sB) {
#pragma unroll
    for (int s = 0; s < 2; ++s) {
      const int ck = ((s * 4 + hi) ^ frx) * 8;
      bf16x8 a[MI], b[NJ];
#pragma unroll
      for (int i = 0; i < MI; ++i)
        a[i] = *(const bf16x8*)(sA + (wm + i * 16 + fr) * 64 + ck);
#pragma unroll
      for (int j = 0; j < NJ; ++j)
        b[j] = *(const bf16x8*)(sB + (wn + j * 16 + fr) * 64 + ck);
#pragma unroll
      for (int i = 0; i < MI; ++i)
#pragma unroll
        for (int j = 0; j < NJ; ++j)
          acc[i][j] = __builtin_amdgcn_mfma_f32_16x16x32_bf16(a[i], b[j], acc[i][j], 0, 0, 0);
    }
  };

  const int T = K >> 6;                // call sites: T even
  stage(As0, Bs0);
  __syncthreads();
  for (int k = 0; k < T; k += 2) {
    stage(As1, Bs1);
    compute(As0, Bs0);
    __syncthreads();
    if (k + 2 < T) stage(As0, Bs0);
    compute(As1, Bs1);
    __syncthreads();
  }

#pragma unroll
  for (int j = 0; j < NJ; ++j) {
    const int col = bn * BN + wn + j * 16 + fr;
    const float bv = bias[col];
#pragma unroll
    for (int i = 0; i < MI; ++i) {
#pragma unroll
      for (int r = 0; r < 4; ++r) {
        const int row = bm * BM + wm + i * 16 + hi * 4 + r;
        const float x = acc[i][j][r] + bv;
        const size_t idx = (size_t)row * N + col;
        if constexpr (EP == 0) {
          outb[idx] = f2bf(tanh_fast(x));
        } else {
          const float att = sigmoid_fast(x);
          outf[idx] = att;
          sa[idx] = f2bf(bf2f(obsb[idx]) * att);
        }
      }
    }
  }
}

// ---------------- G4: BK=32, 3-buffer depth-2 prefetch, counted vmcnt ----------------
// R9: removes R2's per-barrier vmcnt(0) drain. Three 8KB buffer-pairs (48KB,
// 2 blk/CU grid-capped); glds for tile t+2 issued two compute periods (~800cy)
// before use >= worst-case HBM latency, and the per-tile wait is vmcnt(4)
// (newest tile's 4 glds stay in flight - T4: never drain to 0 in the loop).
// Race discipline: lgkmcnt(0) BEFORE each s_barrier guarantees every wave's
// ds_reads are serviced before any wave issues the glds that recycles that
// buffer (the m152 failure mode); sched_barrier(0) pins hipcc (rule #18).
// Tail: clamped dummy stages into buffers never read again; final vmcnt(0).
// Requires (T-1)%3==0: T = K/32 = 64 for G4. Swizzle (4 chunks/row): LDS slot
// c of row r holds global chunk c^(r&3); read slot = hi^(fr&3). Row stride
// 64B + XOR spreads the 64 lanes' b128 starts over 8 bank-groups (same
// uniformity as the R2 layout that measured 0 conflicts).
// EP2 epilogue: atomicAdd(vout[row], sum_col tanh(x+bias)*W3[col]).
__global__ __launch_bounds__(256, 2)
void gemm_k32v(const u16* __restrict__ A, const u16* __restrict__ Bt,
               int K,
               const float* __restrict__ bias,
               const float* __restrict__ W3, const float* __restrict__ b3,
               float* __restrict__ vout) {
  __shared__ __align__(16) u16 As0[4096], Bs0[4096];   // 128 rows x 32 cols, 8KB each
  __shared__ __align__(16) u16 As1[4096], Bs1[4096];
  __shared__ __align__(16) u16 As2[4096], Bs2[4096];   // total 48KB

  const int tid = threadIdx.x;
  const int lane = tid & 63;
  const int wave = tid >> 6;
  const int bm = blockIdx.x, bn = blockIdx.y;

  const int r0 = tid >> 2;                       // staging row 0..63
  const int kcs = ((tid & 3) ^ (r0 & 3)) * 8;    // pre-swizzled source chunk
  const u16* gA = A + (size_t)(bm * 128 + r0) * K + kcs;
  const u16* gB = Bt + (size_t)(bn * 128 + r0) * K + kcs;

  const int wm = (wave >> 1) * 64;
  const int wn = (wave & 1) * 64;
  const int fr = lane & 15;
  const int hi = lane >> 4;
  const int ck = (hi ^ (fr & 3)) * 8;            // swizzled read chunk offset

  f32x4 acc[4][4];
#pragma unroll
  for (int i = 0; i < 4; ++i)
#pragma unroll
    for (int j = 0; j < 4; ++j)
      acc[i][j] = (f32x4){0.f, 0.f, 0.f, 0.f};

  auto stage = [&](int ts, u16* __restrict__ dA, u16* __restrict__ dB) {
    const size_t o = (size_t)ts * 32;
    glds16(gA + o, dA + tid * 8);                        // rows 0..63
    glds16(gA + o + (size_t)64 * K, dA + 2048 + tid * 8); // rows 64..127
    glds16(gB + o, dB + tid * 8);
    glds16(gB + o + (size_t)64 * K, dB + 2048 + tid * 8);
  };

  auto compute = [&](const u16* sA, const u16* sB) {
    bf16x8 a[4], b[4];
#pragma unroll
    for (int j = 0; j < 4; ++j)
      b[j] = *(const bf16x8*)(sB + (wn + j * 16 + fr) * 32 + ck);
#pragma unroll
    for (int i = 0; i < 4; ++i)
      a[i] = *(const bf16x8*)(sA + (wm + i * 16 + fr) * 32 + ck);
#pragma unroll
    for (int i = 0; i < 4; ++i)
#pragma unroll
      for (int j = 0; j < 4; ++j)
        acc[i][j] = __builtin_amdgcn_mfma_f32_16x16x32_bf16(a[i], b[j], acc[i][j], 0, 0, 0);
  };

  auto waitb = [] {
    asm volatile("s_waitcnt vmcnt(4) lgkmcnt(0)" ::: "memory");
    __builtin_amdgcn_sched_barrier(0);
    __builtin_amdgcn_s_barrier();
    __builtin_amdgcn_sched_barrier(0);
  };

  const int T = K >> 5;                // 64; (T-1)%3 == 0 required
  stage(0, As0, Bs0);
  stage(1, As1, Bs1);
  waitb();                             // tile0 ready; tile1 in flight
  for (int t = 0; t < T - 1; t += 3) {
    stage(t + 2 < T ? t + 2 : T - 1, As2, Bs2); compute(As0, Bs0); waitb();
    stage(t + 3 < T ? t + 3 : T - 1, As0, Bs0); compute(As1, Bs1); waitb();
    stage(t + 4 < T ? t + 4 : T - 1, As1, Bs1); compute(As2, Bs2); waitb();
  }
  compute(As0, Bs0);                   // tile T-1 ((T-1)%3==0 -> buf0)
  asm volatile("s_waitcnt vmcnt(0)" ::: "memory");   // drain tail dummies

  // epilogue: row = bm*128 + wm + i*16 + hi*4 + r, col = bn*128 + wn + j*16 + fr
  float vpart[4][4];
#pragma unroll
  for (int i = 0; i < 4; ++i)
#pragma unroll
    for (int r = 0; r < 4; ++r) vpart[i][r] = 0.f;
#pragma unroll
  for (int j = 0; j < 4; ++j) {
    const int col = bn * 128 + wn + j * 16 + fr;
    const float bv = bias[col];
    const float w3 = W3[col];
#pragma unroll
    for (int i = 0; i < 4; ++i)
#pragma unroll
      for (int r = 0; r < 4; ++r)
        vpart[i][r] += tanh_fast(acc[i][j][r] + bv) * w3;
  }
  const bool lead = (fr == 0);
  const bool addb = (bn == 0) && ((wave & 1) == 0);
#pragma unroll
  for (int i = 0; i < 4; ++i)
#pragma unroll
    for (int r = 0; r < 4; ++r) {
      float p = vpart[i][r];
      p += __shfl_xor(p, 8);
      p += __shfl_xor(p, 4);
      p += __shfl_xor(p, 2);
      p += __shfl_xor(p, 1);
      if (lead) {
        const int row = bm * 128 + wm + i * 16 + hi * 4 + r;
        atomicAdd(vout + row, addb ? p + b3[0] : p);
      }
    }
}

extern "C" void kernel_launch(void* const* d_in, const int* in_sizes, int n_in,
                              void* d_out, int out_size, void* d_ws, size_t ws_size,
                              hipStream_t stream) {
  const float* obs   = (const float*)d_in[0];   // [4096,1024]
  const float* We    = (const float*)d_in[1];   // [512,1024]
  const float* be    = (const float*)d_in[2];   // [512]
  const float* attnW = (const float*)d_in[3];   // [1024,512,2]
  const float* attnb = (const float*)d_in[4];   // [1024,2]
  const float* W1    = (const float*)d_in[5];   // [2048,1024]
  const float* b1    = (const float*)d_in[6];   // [2048]
  const float* W2    = (const float*)d_in[7];   // [2048,2048]
  const float* b2    = (const float*)d_in[8];   // [2048]
  const float* W3    = (const float*)d_in[9];   // [1,2048]
  const float* b3    = (const float*)d_in[10];  // [1]
  float* out = (float*)d_out;                   // [4096] v, then [4096,1024] attention

  char* ws = (char*)d_ws;
  u16*   We_b  = (u16*)(ws + 0x00000000);   // 1 MB
  u16*   Wd_b  = (u16*)(ws + 0x00100000);   // 1 MB
  u16*   W1_b  = (u16*)(ws + 0x00200000);   // 4 MB
  u16*   W2_b  = (u16*)(ws + 0x00600000);   // 8 MB
  float* bd    = (float*)(ws + 0x00E00000); // 4 KB
  u16*   obs_b = (u16*)(ws + 0x00E01000);   // 8 MB
  u16*   e_b   = (u16*)(ws + 0x01601000);   // 4 MB
  u16*   sa_b  = (u16*)(ws + 0x01A01000);   // 8 MB
  u16*   h1_b  = (u16*)(ws + 0x02201000);   // 16 MB (end ~50 MB; h2 never stored)

  // prep: all casts + attn weight prep + zero v, one launch
  prep_kernel<<<11264, 256, 0, stream>>>(obs, We, W1, W2, attnW, attnb,
                                         obs_b, We_b, W1_b, W2_b, Wd_b, bd, out);

  // G1: e = tanh(obs @ We^T + be)   [4096,512]  64x64 -> 512 blocks
  gemm_bt<64, 64, 0><<<dim3(64, 8), 256, 0, stream>>>(
      obs_b, We_b, 512, 1024, be, e_b, nullptr, nullptr, nullptr);
  // G2: att = sigmoid(e @ Wd^T + bd); sa = obs*att   [4096,1024]  128x64 -> 512 blocks
  gemm_bt<128, 64, 1><<<dim3(32, 16), 256, 0, stream>>>(
      e_b, Wd_b, 1024, 512, bd, nullptr, out + 4096, obs_b, sa_b);
  // G3: h1 = tanh(sa @ W1^T + b1)   [4096,2048]  128x128 -> 512 blocks (R2 path)
  gemm_bt<128, 128, 0><<<dim3(32, 16), 256, 0, stream>>>(
      sa_b, W1_b, 2048, 1024, b1, h1_b, nullptr, nullptr, nullptr);
  // G4+v: v = tanh(h1 @ W2^T + b2) @ W3 + b3 — BK=32 depth-2 pipeline
  gemm_k32v<<<dim3(32, 16), 256, 0, stream>>>(
      h1_b, W2_b, 2048, b2, W3, b3, out);
}

// Round 10
// 193.598 us; speedup vs baseline: 4.0632x; 1.0150x over previous
//
#include <hip/hip_runtime.h>
#include <hip/hip_bf16.h>

typedef unsigned short u16;
typedef u16 u16x4 __attribute__((ext_vector_type(4)));
typedef u16 u16x8 __attribute__((ext_vector_type(8)));
typedef __bf16 bf16x8 __attribute__((ext_vector_type(8)));
typedef float f32x4 __attribute__((ext_vector_type(4)));

__device__ __forceinline__ u16 f2bf(float f) {
  unsigned u = __float_as_uint(f);
  u += 0x7FFFu + ((u >> 16) & 1u);   // round-to-nearest-even
  return (u16)(u >> 16);
}
__device__ __forceinline__ float bf2f(u16 h) {
  return __uint_as_float(((unsigned)h) << 16);
}
__device__ __forceinline__ float tanh_fast(float x) {
  float t = __expf(2.0f * x);
  return 1.0f - 2.0f / (t + 1.0f);
}
__device__ __forceinline__ float sigmoid_fast(float x) {
  return 1.0f / (1.0f + __expf(-x));
}

// async global->LDS, 16B per lane. Dest is wave-uniform base + lane*16; our
// per-lane dest (= base + tid*8 u16) is linear in tid, matching exactly.
__device__ __forceinline__ void glds16(const u16* g, u16* l) {
  __builtin_amdgcn_global_load_lds(
      (const __attribute__((address_space(1))) unsigned int*)g,
      (__attribute__((address_space(3))) unsigned int*)l, 16, 0, 0);
}

__device__ __forceinline__ void cvt4(const float* __restrict__ s, u16* __restrict__ d, int q) {
  float4 v = ((const float4*)s)[q];
  u16x4 o = { f2bf(v.x), f2bf(v.y), f2bf(v.z), f2bf(v.w) };
  ((u16x4*)d)[q] = o;
}

// ---------------- slim prep: obs/We casts + attn weight-diff + zero v ----------------
// W1/W2 casts moved into rider blocks of G1/G2 (launch-order slack: W1 needed
// first by G3, W2 by G4; G1/G2 run at ~0.8 of 6.3 TB/s -> riders hide in their
// bandwidth shadow). 1,310,720 quads -> 5120 blocks.
__global__ __launch_bounds__(256)
void prep_kernel(const float* __restrict__ obs, const float* __restrict__ We,
                 const float* __restrict__ aW, const float* __restrict__ ab,
                 u16* __restrict__ obs_b, u16* __restrict__ We_b,
                 u16* __restrict__ Wd, float* __restrict__ bd,
                 float* __restrict__ vzero) {
  int q = blockIdx.x * 256 + threadIdx.x;          // quad (4-element) index
  if (q < 1024) ((float4*)vzero)[q] = (float4){0.f, 0.f, 0.f, 0.f};  // zero v[4096]
  if (q < 1048576) { cvt4(obs, obs_b, q); return; }                 // 4096*1024
  q -= 1048576;
  if (q < 131072) { cvt4(We, We_b, q); return; }                    // 512*1024
  q -= 131072;
  if (q < 131072) {                                                  // Wd: 1024*512
    int i0 = q * 4;
    int o = i0 >> 9, e0 = i0 & 511;
    const float* p = aW + (size_t)o * 1024 + e0 * 2;
    float4 v0 = *(const float4*)p;
    float4 v1 = *(const float4*)(p + 4);
    u16x4 od = { f2bf(v0.y - v0.x), f2bf(v0.w - v0.z),
                 f2bf(v1.y - v1.x), f2bf(v1.w - v1.z) };
    *(u16x4*)(Wd + i0) = od;
    if (q < 256) {                                                   // bd: 1024
      float4 a0 = *(const float4*)(ab + q * 8);
      float4 a1 = *(const float4*)(ab + q * 8 + 4);
      float4 ob = { a0.y - a0.x, a0.w - a0.z, a1.y - a1.x, a1.w - a1.z };
      *(float4*)(bd + q * 4) = ob;
    }
  }
}

// ---------------- R2-proven bf16 MFMA GEMM + optional cast-rider blocks ----------------
// C = A[M,K] * Bt[N,K]^T, BK=64. 2-phase dbuf, glds staging, both-sides XOR
// swizzle (measured 0 bank conflicts), one vmcnt-drain barrier per K-step.
// GYM/CEX: blocks with blockIdx.y >= GYM (CEX extra grid rows) are cast
// riders - they grid-stride cvt4(castS->castD) and exit before any barrier.
// Block-uniform branch; LDS residency (32-48KB/block -> 3-5 blk/CU) lets
// riders co-run with GEMM blocks instead of queueing.
// EP 0: outb = bf16(tanh(x + bias[col]))
// EP 1: att = sigmoid(x + bias[col]); outf = att; sa = bf16(obs_b * att)
// EP 2: fused v-dot: atomicAdd(vout[row], sum_col tanh(x+bias)*W3[col])
template <int BM, int BN, int EP, int GYM, int CEX>
__global__ __launch_bounds__(256, 2)
void gemm_bt(const u16* __restrict__ A, const u16* __restrict__ Bt,
             int N, int K,
             const float* __restrict__ bias,
             u16* __restrict__ outb, float* __restrict__ outf,
             const u16* __restrict__ obsb, u16* __restrict__ sa,
             const float* __restrict__ W3, const float* __restrict__ b3,
             float* __restrict__ vout,
             const float* __restrict__ castS, u16* __restrict__ castD, int castQ) {
  constexpr int CA = BM / 32;
  constexpr int CB = BN / 32;
  constexpr int MI = BM / 32;
  constexpr int NJ = BN / 32;

  if constexpr (CEX > 0) {
    if ((int)blockIdx.y >= GYM) {      // cast rider block
      const int idx = ((int)blockIdx.y - GYM) * (int)gridDim.x + (int)blockIdx.x;
      const int stride = (int)gridDim.x * CEX * 256;
      for (int q = idx * 256 + (int)threadIdx.x; q < castQ; q += stride)
        cvt4(castS, castD, q);
      return;
    }
  }

  __shared__ __align__(16) u16 As0[BM * 64];
  __shared__ __align__(16) u16 Bs0[BN * 64];
  __shared__ __align__(16) u16 As1[BM * 64];
  __shared__ __align__(16) u16 Bs1[BN * 64];

  const int tid = threadIdx.x;
  const int lane = tid & 63;
  const int wave = tid >> 6;
  const int bm = blockIdx.x, bn = blockIdx.y;

  const int r0 = tid >> 3;
  const int kcs = ((tid & 7) ^ (r0 & 7)) * 8;    // pre-swizzled source chunk

  const u16* gA = A + (size_t)(bm * BM + r0) * K + kcs;
  const u16* gB = Bt + (size_t)(bn * BN + r0) * K + kcs;

  const int wm = (wave >> 1) * (BM / 2);
  const int wn = (wave & 1) * (BN / 2);
  const int fr = lane & 15;
  const int hi = lane >> 4;
  const int frx = fr & 7;

  f32x4 acc[MI][NJ];
#pragma unroll
  for (int i = 0; i < MI; ++i)
#pragma unroll
    for (int j = 0; j < NJ; ++j)
      acc[i][j] = (f32x4){0.f, 0.f, 0.f, 0.f};

  auto stage = [&](u16* __restrict__ dA, u16* __restrict__ dB) {
#pragma unroll
    for (int q = 0; q < CA; ++q)
      glds16(gA + (size_t)q * 32 * K, dA + tid * 8 + q * 2048);
#pragma unroll
    for (int q = 0; q < CB; ++q)
      glds16(gB + (size_t)q * 32 * K, dB + tid * 8 + q * 2048);
    gA += 64; gB += 64;
  };

  auto compute = [&](const u16* sA, const u16* sB) {
#pragma unroll
    for (int s = 0; s < 2; ++s) {
      const int ck = ((s * 4 + hi) ^ frx) * 8;   // swizzled 16B-chunk offset
      bf16x8 a[MI], b[NJ];
#pragma unroll
      for (int i = 0; i < MI; ++i)
        a[i] = *(const bf16x8*)(sA + (wm + i * 16 + fr) * 64 + ck);
#pragma unroll
      for (int j = 0; j < NJ; ++j)
        b[j] = *(const bf16x8*)(sB + (wn + j * 16 + fr) * 64 + ck);
#pragma unroll
      for (int i = 0; i < MI; ++i)
#pragma unroll
        for (int j = 0; j < NJ; ++j)
          acc[i][j] = __builtin_amdgcn_mfma_f32_16x16x32_bf16(a[i], b[j], acc[i][j], 0, 0, 0);
    }
  };

  const int T = K >> 6;                // call sites: T even
  stage(As0, Bs0);
  __syncthreads();
  for (int k = 0; k < T; k += 2) {
    stage(As1, Bs1);                   // next tile in flight across 32 MFMAs
    compute(As0, Bs0);
    __syncthreads();                   // vmcnt(0) drain: tile k+1 ready
    if (k + 2 < T) stage(As0, Bs0);
    compute(As1, Bs1);
    __syncthreads();
  }

  // epilogue: row = bm*BM + wm + i*16 + hi*4 + r, col = bn*BN + wn + j*16 + fr
  if constexpr (EP == 2) {
    float vpart[MI][4];
#pragma unroll
    for (int i = 0; i < MI; ++i)
#pragma unroll
      for (int r = 0; r < 4; ++r) vpart[i][r] = 0.f;
#pragma unroll
    for (int j = 0; j < NJ; ++j) {
      const int col = bn * BN + wn + j * 16 + fr;
      const float bv = bias[col];
      const float w3 = W3[col];
#pragma unroll
      for (int i = 0; i < MI; ++i)
#pragma unroll
        for (int r = 0; r < 4; ++r)
          vpart[i][r] += tanh_fast(acc[i][j][r] + bv) * w3;
    }
    const bool lead = (fr == 0);
    const bool addb = (bn == 0) && ((wave & 1) == 0);
#pragma unroll
    for (int i = 0; i < MI; ++i)
#pragma unroll
      for (int r = 0; r < 4; ++r) {
        float p = vpart[i][r];
        p += __shfl_xor(p, 8);
        p += __shfl_xor(p, 4);
        p += __shfl_xor(p, 2);
        p += __shfl_xor(p, 1);
        if (lead) {
          const int row = bm * BM + wm + i * 16 + hi * 4 + r;
          atomicAdd(vout + row, addb ? p + b3[0] : p);
        }
      }
  } else {
#pragma unroll
    for (int j = 0; j < NJ; ++j) {
      const int col = bn * BN + wn + j * 16 + fr;
      const float bv = bias[col];
#pragma unroll
      for (int i = 0; i < MI; ++i) {
#pragma unroll
        for (int r = 0; r < 4; ++r) {
          const int row = bm * BM + wm + i * 16 + hi * 4 + r;
          const float x = acc[i][j][r] + bv;
          const size_t idx = (size_t)row * N + col;
          if constexpr (EP == 0) {
            outb[idx] = f2bf(tanh_fast(x));
          } else {
            const float att = sigmoid_fast(x);
            outf[idx] = att;
            sa[idx] = f2bf(bf2f(obsb[idx]) * att);
          }
        }
      }
    }
  }
}

extern "C" void kernel_launch(void* const* d_in, const int* in_sizes, int n_in,
                              void* d_out, int out_size, void* d_ws, size_t ws_size,
                              hipStream_t stream) {
  const float* obs   = (const float*)d_in[0];   // [4096,1024]
  const float* We    = (const float*)d_in[1];   // [512,1024]
  const float* be    = (const float*)d_in[2];   // [512]
  const float* attnW = (const float*)d_in[3];   // [1024,512,2]
  const float* attnb = (const float*)d_in[4];   // [1024,2]
  const float* W1    = (const float*)d_in[5];   // [2048,1024]
  const float* b1    = (const float*)d_in[6];   // [2048]
  const float* W2    = (const float*)d_in[7];   // [2048,2048]
  const float* b2    = (const float*)d_in[8];   // [2048]
  const float* W3    = (const float*)d_in[9];   // [1,2048]
  const float* b3    = (const float*)d_in[10];  // [1]
  float* out = (float*)d_out;                   // [4096] v, then [4096,1024] attention

  char* ws = (char*)d_ws;
  u16*   We_b  = (u16*)(ws + 0x00000000);   // 1 MB
  u16*   Wd_b  = (u16*)(ws + 0x00100000);   // 1 MB
  u16*   W1_b  = (u16*)(ws + 0x00200000);   // 4 MB
  u16*   W2_b  = (u16*)(ws + 0x00600000);   // 8 MB
  float* bd    = (float*)(ws + 0x00E00000); // 4 KB
  u16*   obs_b = (u16*)(ws + 0x00E01000);   // 8 MB
  u16*   e_b   = (u16*)(ws + 0x01601000);   // 4 MB
  u16*   sa_b  = (u16*)(ws + 0x01A01000);   // 8 MB
  u16*   h1_b  = (u16*)(ws + 0x02201000);   // 16 MB (end ~50 MB; h2 never stored)

  // prep (slim): obs/We casts + attn weight prep + zero v
  prep_kernel<<<5120, 256, 0, stream>>>(obs, We, attnW, attnb,
                                        obs_b, We_b, Wd_b, bd, out);

  // G1: e = tanh(obs @ We^T + be)  [4096,512] 64x64, 512 GEMM blocks
  //     + 128 rider blocks casting W1 -> W1_b (needed first by G3)
  gemm_bt<64, 64, 0, 8, 2><<<dim3(64, 10), 256, 0, stream>>>(
      obs_b, We_b, 512, 1024, be, e_b, nullptr, nullptr, nullptr,
      nullptr, nullptr, nullptr, W1, W1_b, 524288);
  // G2: att = sigmoid(e @ Wd^T + bd); sa = obs*att  [4096,1024] 128x64
  //     + 128 rider blocks casting W2 -> W2_b (needed first by G4)
  gemm_bt<128, 64, 1, 16, 4><<<dim3(32, 20), 256, 0, stream>>>(
      e_b, Wd_b, 1024, 512, bd, nullptr, out + 4096, obs_b, sa_b,
      nullptr, nullptr, nullptr, W2, W2_b, 1048576);
  // G3: h1 = tanh(sa @ W1^T + b1)  [4096,2048] 128x128 (R2-exact path)
  gemm_bt<128, 128, 0, 16, 0><<<dim3(32, 16), 256, 0, stream>>>(
      sa_b, W1_b, 2048, 1024, b1, h1_b, nullptr, nullptr, nullptr,
      nullptr, nullptr, nullptr, nullptr, nullptr, 0);
  // G4+v: v = tanh(h1 @ W2^T + b2) @ W3 + b3 (R2-exact path; h2 never stored)
  gemm_bt<128, 128, 2, 16, 0><<<dim3(32, 16), 256, 0, stream>>>(
      h1_b, W2_b, 2048, 2048, b2, nullptr, nullptr, nullptr, nullptr,
      W3, b3, out, nullptr, nullptr, 0);
}